// Round 1
// baseline (194.036 us; speedup 1.0000x reference)
//
#include <hip/hip_runtime.h>
#include <hip/hip_bf16.h>

#define Bimg 32
#define Mgt 256
#define Nprop 4000
#define KBOX (Nprop + Mgt)   // 4256
#define NCLS 80
#define NSORT 8192
#define BATCH 512
#define NFG_CAP 128

// ---------------- Kernel A: IoU + matcher ----------------
__global__ __launch_bounds__(256) void iou_match_kernel(
    const float* __restrict__ gt_boxes,     // [B,M,4]
    const float* __restrict__ prop_boxes,   // [B,N,4]
    float* __restrict__ out_iou,            // [B,M,K]
    float* __restrict__ out_midx,           // [B,K] (float-encoded int)
    float* __restrict__ out_mlab)           // [B,K] (float-encoded int)
{
    const int b = blockIdx.y;
    const int k = blockIdx.x * 256 + threadIdx.x;

    __shared__ float4 gbox[Mgt];
    __shared__ float  garea[Mgt];
    {
        int m = threadIdx.x;   // exactly 256 threads, 256 gt boxes
        float4 g = ((const float4*)(gt_boxes + (size_t)b * Mgt * 4))[m];
        gbox[m] = g;
        garea[m] = (g.z - g.x) * (g.w - g.y);
    }
    __syncthreads();

    float4 bx = make_float4(0.f, 0.f, 0.f, 0.f);
    if (k < KBOX) {
        if (k < Nprop) bx = ((const float4*)(prop_boxes + (size_t)b * Nprop * 4))[k];
        else           bx = gbox[k - Nprop];
    }
    const float a2 = (bx.z - bx.x) * (bx.w - bx.y);

    float best = -1.0f;
    int   bidx = 0;
    float* iou_col = out_iou + (size_t)b * Mgt * KBOX + k;

    for (int m = 0; m < Mgt; ++m) {
        float4 g = gbox[m];
        float ltx = fmaxf(g.x, bx.x), lty = fmaxf(g.y, bx.y);
        float rbx = fminf(g.z, bx.z), rby = fminf(g.w, bx.w);
        float w = fmaxf(rbx - ltx, 0.0f);
        float h = fmaxf(rby - lty, 0.0f);
        float inter = w * h;
        float uni = garea[m] + a2 - inter;
        float iou = (inter > 0.0f) ? (inter / uni) : 0.0f;
        if (k < KBOX) iou_col[(size_t)m * KBOX] = iou;
        if (iou > best) { best = iou; bidx = m; }   // strict > == first-argmax
    }

    if (k < KBOX) {
        out_midx[(size_t)b * KBOX + k] = (float)bidx;
        out_mlab[(size_t)b * KBOX + k] = (best >= 0.5f) ? 1.0f : 0.0f;
    }
}

// ---------------- Kernel B: subsample (sort + rank + compact) ----------------
__global__ __launch_bounds__(1024) void sample_kernel(
    const int*   __restrict__ gt_classes,   // [B,M]
    const float* __restrict__ pri,          // [B,K]
    const float* __restrict__ out_midx,     // [B,K]
    const float* __restrict__ out_mlab,     // [B,K]
    float* __restrict__ out_idx,            // [B,512]
    float* __restrict__ out_lab)            // [B,512]
{
    const int b   = blockIdx.x;
    const int tid = threadIdx.x;

    __shared__ unsigned long long skey[NSORT];   // 64 KB
    __shared__ int  clsArr[KBOX];                // 17 KB
    __shared__ unsigned char selOrig[KBOX];      // 4.2 KB
    __shared__ int  part[1024];                  // 4 KB

    // build keys: high32 = priority bits (pri>=0 -> monotone as uint),
    // low32 = 0xFFFFFFFF - index  (desc sort => ties prefer lower index)
    for (int i = tid; i < NSORT; i += 1024) {
        unsigned long long key = 0ull;           // pads sort last (desc)
        if (i < KBOX) {
            float p = pri[(size_t)b * KBOX + i];
            unsigned pb = __float_as_uint(p);
            key = ((unsigned long long)pb << 32) |
                  (unsigned long long)(0xFFFFFFFFu - (unsigned)i);
            float ml = out_mlab[(size_t)b * KBOX + i];
            int   mi = (int)out_midx[(size_t)b * KBOX + i];
            clsArr[i] = (ml != 0.0f) ? gt_classes[b * Mgt + mi] : NCLS;
        }
        skey[i] = key;
    }
    __syncthreads();

    // bitonic sort, descending
    for (int k2 = 2; k2 <= NSORT; k2 <<= 1) {
        for (int j = k2 >> 1; j > 0; j >>= 1) {
            for (int i = tid; i < NSORT; i += 1024) {
                int ixj = i ^ j;
                if (ixj > i) {
                    unsigned long long a = skey[i], c = skey[ixj];
                    bool up = ((i & k2) == 0);
                    if (up ? (a < c) : (a > c)) { skey[i] = c; skey[ixj] = a; }
                }
            }
            __syncthreads();
        }
    }

    // packed fg/bg exclusive scan over sorted order (fg in low16, bg in high16)
    int local[8];
    int acc = 0;
#pragma unroll
    for (int q = 0; q < 8; ++q) {
        int i = tid * 8 + q;
        int contrib = 0;
        if (i < KBOX) {
            int kk = (int)(0xFFFFFFFFu - (unsigned)(skey[i] & 0xFFFFFFFFull));
            contrib = (clsArr[kk] < NCLS) ? 1 : (1 << 16);
        }
        local[q] = acc;
        acc += contrib;
    }
    part[tid] = acc;
    __syncthreads();
    for (int off = 1; off < 1024; off <<= 1) {
        int v = part[tid];
        int add = (tid >= off) ? part[tid - off] : 0;
        __syncthreads();
        part[tid] = v + add;
        __syncthreads();
    }
    const int excl   = (tid > 0) ? part[tid - 1] : 0;
    const int totals = part[1023];
    const int total_fg = totals & 0xFFFF;
    const int total_bg = (totals >> 16) & 0xFFFF;
    const int num_fg = min(total_fg, NFG_CAP);
    const int num_bg = min(total_bg, BATCH - num_fg);

#pragma unroll
    for (int q = 0; q < 8; ++q) {
        int i = tid * 8 + q;
        if (i >= KBOX) continue;
        int kk = (int)(0xFFFFFFFFu - (unsigned)(skey[i] & 0xFFFFFFFFull));
        int c  = clsArr[kk];
        int r  = excl + local[q];
        int fgrank = r & 0xFFFF;
        int bgrank = (r >> 16) & 0xFFFF;
        bool fg  = (c < NCLS);
        bool sel = fg ? (fgrank < num_fg) : (bgrank < num_bg);
        selOrig[kk] = sel ? 1 : 0;
        if (sel) {
            int p = min(fgrank, num_fg) + min(bgrank, num_bg); // # selected before i
            out_idx[b * BATCH + p] = (float)kk;
            out_lab[b * BATCH + p] = (float)c;
        }
    }

    // tail padding (labels = -1), only if fewer than 512 selected
    const int total_sel = num_fg + num_bg;
    if (total_sel < BATCH) {
        __syncthreads();
        int loc2[8];
        int acc2 = 0;
#pragma unroll
        for (int q = 0; q < 8; ++q) {
            int kk = tid * 8 + q;
            int contrib = (kk < KBOX && !selOrig[kk]) ? 1 : 0;
            loc2[q] = acc2;
            acc2 += contrib;
        }
        part[tid] = acc2;
        __syncthreads();
        for (int off = 1; off < 1024; off <<= 1) {
            int v = part[tid];
            int add = (tid >= off) ? part[tid - off] : 0;
            __syncthreads();
            part[tid] = v + add;
            __syncthreads();
        }
        int excl2 = (tid > 0) ? part[tid - 1] : 0;
#pragma unroll
        for (int q = 0; q < 8; ++q) {
            int kk = tid * 8 + q;
            if (kk < KBOX && !selOrig[kk]) {
                int p = total_sel + excl2 + loc2[q];
                if (p < BATCH) {
                    out_idx[b * BATCH + p] = (float)kk;
                    out_lab[b * BATCH + p] = -1.0f;
                }
            }
        }
    }
}

extern "C" void kernel_launch(void* const* d_in, const int* in_sizes, int n_in,
                              void* d_out, int out_size, void* d_ws, size_t ws_size,
                              hipStream_t stream) {
    const float* gt_boxes   = (const float*)d_in[0];
    const float* prop_boxes = (const float*)d_in[1];
    const int*   gt_classes = (const int*)d_in[2];
    const float* rand_pri   = (const float*)d_in[3];

    float* out = (float*)d_out;
    const size_t off_iou  = 0;
    const size_t off_midx = (size_t)Bimg * Mgt * KBOX;       // 34,865,152
    const size_t off_mlab = off_midx + (size_t)Bimg * KBOX;  // +136,192
    const size_t off_idx  = off_mlab + (size_t)Bimg * KBOX;
    const size_t off_lab  = off_idx  + (size_t)Bimg * BATCH;

    dim3 gridA((KBOX + 255) / 256, Bimg);
    iou_match_kernel<<<gridA, 256, 0, stream>>>(
        gt_boxes, prop_boxes,
        out + off_iou, out + off_midx, out + off_mlab);

    sample_kernel<<<Bimg, 1024, 0, stream>>>(
        gt_classes, rand_pri,
        out + off_midx, out + off_mlab,
        out + off_idx, out + off_lab);
}

// Round 2
// 122.374 us; speedup vs baseline: 1.5856x; 1.5856x over previous
//
#include <hip/hip_runtime.h>
#include <hip/hip_bf16.h>

#define Bimg 32
#define Mgt 256
#define Nprop 4000
#define KBOX (Nprop + Mgt)   // 4256
#define NCLS 80
#define BATCH 512
#define NFG_CAP 128
#define NBINS 1024
#define BINCAP 1024

// ---------------- Kernel A: IoU + matcher (4 cols/thread, float4 stores) ----------------
__global__ __launch_bounds__(256) void iou_match_kernel(
    const float* __restrict__ gt_boxes,     // [B,M,4]
    const float* __restrict__ prop_boxes,   // [B,N,4]
    float* __restrict__ out_iou,            // [B,M,K]
    float* __restrict__ out_midx,           // [B,K]
    float* __restrict__ out_mlab)           // [B,K]
{
    const int b = blockIdx.y;
    const int g4 = blockIdx.x * 256 + threadIdx.x;
    const int k0 = g4 * 4;

    __shared__ float4 gbox[Mgt];
    __shared__ float  garea[Mgt];
    {
        int m = threadIdx.x;   // 256 threads, 256 gt boxes
        float4 g = ((const float4*)(gt_boxes + (size_t)b * Mgt * 4))[m];
        gbox[m] = g;
        garea[m] = (g.z - g.x) * (g.w - g.y);
    }
    __syncthreads();
    if (k0 >= KBOX) return;

    float4 bx[4]; float a2[4];
    if (k0 < Nprop) {   // Nprop % 4 == 0, no straddle
        const float4* pp = (const float4*)(prop_boxes + (size_t)b * Nprop * 4);
        #pragma unroll
        for (int c = 0; c < 4; ++c) bx[c] = pp[k0 + c];
    } else {
        #pragma unroll
        for (int c = 0; c < 4; ++c) bx[c] = gbox[k0 - Nprop + c];
    }
    #pragma unroll
    for (int c = 0; c < 4; ++c) a2[c] = (bx[c].z - bx[c].x) * (bx[c].w - bx[c].y);

    float best[4] = {-1.f, -1.f, -1.f, -1.f};
    int   bidx[4] = {0, 0, 0, 0};
    float* orow = out_iou + (size_t)b * Mgt * KBOX + k0;

    for (int m = 0; m < Mgt; ++m) {
        float4 g = gbox[m];
        float ga = garea[m];
        float io[4];
        #pragma unroll
        for (int c = 0; c < 4; ++c) {
            float ltx = fmaxf(g.x, bx[c].x), lty = fmaxf(g.y, bx[c].y);
            float rbx = fminf(g.z, bx[c].z), rby = fminf(g.w, bx[c].w);
            float w = fmaxf(rbx - ltx, 0.0f);
            float h = fmaxf(rby - lty, 0.0f);
            float inter = w * h;
            float uni = ga + a2[c] - inter;
            float iou = (inter > 0.0f) ? (inter / uni) : 0.0f;
            io[c] = iou;
            if (iou > best[c]) { best[c] = iou; bidx[c] = m; }  // strict > == first-argmax
        }
        float4 res = make_float4(io[0], io[1], io[2], io[3]);
        *(float4*)(orow + (size_t)m * KBOX) = res;
    }

    float4 fmidx = make_float4((float)bidx[0], (float)bidx[1], (float)bidx[2], (float)bidx[3]);
    float4 fmlab = make_float4(best[0] >= 0.5f ? 1.f : 0.f,
                               best[1] >= 0.5f ? 1.f : 0.f,
                               best[2] >= 0.5f ? 1.f : 0.f,
                               best[3] >= 0.5f ? 1.f : 0.f);
    *(float4*)(out_midx + (size_t)b * KBOX + k0) = fmidx;
    *(float4*)(out_mlab + (size_t)b * KBOX + k0) = fmlab;
}

// ---------------- Kernel B: histogram-select + 512-sort ----------------
__global__ __launch_bounds__(1024) void sample_kernel(
    const int*   __restrict__ gt_classes,   // [B,M]
    const float* __restrict__ pri,          // [B,K]
    const float* __restrict__ midx,         // [B,K]
    const float* __restrict__ mlab,         // [B,K]
    float* __restrict__ out_idx,            // [B,512]
    float* __restrict__ out_lab)            // [B,512]
{
    const int b   = blockIdx.x;
    const int tid = threadIdx.x;

    __shared__ unsigned long long keys[KBOX];     // 34 KB
    __shared__ unsigned short     clsS[KBOX];     // 8.5 KB
    __shared__ unsigned char      selA[KBOX];     // 4.25 KB
    __shared__ int histP[NBINS];                  // fg low16 | bg high16
    __shared__ int sufP[NBINS];
    __shared__ unsigned long long binFG[BINCAP];  // 8 KB
    __shared__ unsigned long long binBG[BINCAP];  // 8 KB
    __shared__ unsigned long long selKeys[BATCH]; // 4 KB
    __shared__ int cntF, cntB, cntSel, sTF, sTB;

    histP[tid] = 0;
    if (tid == 0) { cntF = 0; cntB = 0; cntSel = 0; sTF = -1; sTB = -1; }
    __syncthreads();

    // build keys, classes, histogram
    for (int i = tid; i < KBOX; i += 1024) {
        float p  = pri[(size_t)b * KBOX + i];
        int   mi = (int)midx[(size_t)b * KBOX + i];
        float ml = mlab[(size_t)b * KBOX + i];
        int c = (ml != 0.0f) ? gt_classes[b * Mgt + mi] : NCLS;
        clsS[i] = (unsigned short)c;
        selA[i] = 0;
        unsigned pb = __float_as_uint(p);   // pri in [0,1): monotone as uint
        keys[i] = ((unsigned long long)pb << 32) |
                  (unsigned long long)(0xFFFFFFFFu - (unsigned)i);
        int bucket = (int)(p * (float)NBINS);
        bucket = min(max(bucket, 0), NBINS - 1);
        atomicAdd(&histP[bucket], (c < NCLS) ? 1 : (1 << 16));
    }
    __syncthreads();

    // inclusive suffix scan of packed histogram
    sufP[tid] = histP[tid];
    __syncthreads();
    for (int off = 1; off < NBINS; off <<= 1) {
        int v = sufP[tid];
        int add = (tid + off < NBINS) ? sufP[tid + off] : 0;
        __syncthreads();
        sufP[tid] = v + add;
        __syncthreads();
    }
    const int total_fg = sufP[0] & 0xFFFF;
    const int total_bg = (sufP[0] >> 16) & 0xFFFF;
    const int num_fg = min(total_fg, NFG_CAP);
    const int num_bg = min(total_bg, BATCH - num_fg);

    // threshold bins: largest t with suffix_count(t) >= target
    {
        int sf  = sufP[tid] & 0xFFFF;
        int sfn = (tid < NBINS - 1) ? (sufP[tid + 1] & 0xFFFF) : 0;
        if (num_fg > 0 && sf >= num_fg && sfn < num_fg) sTF = tid;
        int sb  = (sufP[tid] >> 16) & 0xFFFF;
        int sbn = (tid < NBINS - 1) ? ((sufP[tid + 1] >> 16) & 0xFFFF) : 0;
        if (num_bg > 0 && sb >= num_bg && sbn < num_bg) sTB = tid;
    }
    __syncthreads();
    const int tF = sTF, tB = sTB;
    const int aboveF = (tF >= 0 && tF < NBINS - 1) ? (sufP[tF + 1] & 0xFFFF) : 0;
    const int aboveB = (tB >= 0 && tB < NBINS - 1) ? ((sufP[tB + 1] >> 16) & 0xFFFF) : 0;
    const int needF = num_fg - aboveF;
    const int needB = num_bg - aboveB;

    // selection: above threshold bin -> selected; in threshold bin -> collect
    for (int i = tid; i < KBOX; i += 1024) {
        unsigned long long key = keys[i];
        float p = __uint_as_float((unsigned)(key >> 32));
        int bucket = (int)(p * (float)NBINS);
        bucket = min(max(bucket, 0), NBINS - 1);
        if (clsS[i] < NCLS) {
            if (tF >= 0) {
                if (bucket > tF) selA[i] = 1;
                else if (bucket == tF) { int j = atomicAdd(&cntF, 1); if (j < BINCAP) binFG[j] = key; }
            }
        } else {
            if (tB >= 0) {
                if (bucket > tB) selA[i] = 1;
                else if (bucket == tB) { int j = atomicAdd(&cntB, 1); if (j < BINCAP) binBG[j] = key; }
            }
        }
    }
    __syncthreads();

    // exact rank inside the threshold bins (all 64-bit keys distinct)
    {
        int cf = min(cntF, BINCAP);
        for (int j = tid; j < cf; j += 1024) {
            unsigned long long key = binFG[j];
            int rank = 0;
            for (int l = 0; l < cf; ++l) rank += (binFG[l] > key) ? 1 : 0;
            if (rank < needF) { unsigned kk = 0xFFFFFFFFu - (unsigned)(key & 0xFFFFFFFFull); selA[kk] = 1; }
        }
        int cb = min(cntB, BINCAP);
        for (int j = tid; j < cb; j += 1024) {
            unsigned long long key = binBG[j];
            int rank = 0;
            for (int l = 0; l < cb; ++l) rank += (binBG[l] > key) ? 1 : 0;
            if (rank < needB) { unsigned kk = 0xFFFFFFFFu - (unsigned)(key & 0xFFFFFFFFull); selA[kk] = 1; }
        }
    }
    __syncthreads();

    // compact selected keys (order fixed by the sort below)
    const int total_sel = num_fg + num_bg;
    if (tid < BATCH && tid >= total_sel) selKeys[tid] = 0ull;
    for (int i = tid; i < KBOX; i += 1024) {
        if (selA[i]) {
            int p = atomicAdd(&cntSel, 1);
            selKeys[p] = keys[i];
        }
    }
    __syncthreads();

    // bitonic sort 512 keys, descending (zeros sort last)
    for (int k2 = 2; k2 <= BATCH; k2 <<= 1) {
        for (int j = k2 >> 1; j > 0; j >>= 1) {
            if (tid < BATCH) {
                int i = tid, ixj = i ^ j;
                if (ixj > i) {
                    unsigned long long a = selKeys[i], c2 = selKeys[ixj];
                    bool up = ((i & k2) == 0);
                    if (up ? (a < c2) : (a > c2)) { selKeys[i] = c2; selKeys[ixj] = a; }
                }
            }
            __syncthreads();
        }
    }

    if (tid < BATCH) {
        unsigned long long key = selKeys[tid];
        if (key != 0ull) {
            unsigned kk = 0xFFFFFFFFu - (unsigned)(key & 0xFFFFFFFFull);
            out_idx[b * BATCH + tid] = (float)kk;
            out_lab[b * BATCH + tid] = (float)clsS[kk];
        }
    }

    // tail padding (labels = -1): lowest-index non-selected, only if < 512 selected
    if (total_sel < BATCH) {
        __syncthreads();
        int loc[5]; int acc = 0;
        #pragma unroll
        for (int q = 0; q < 5; ++q) {
            int i = tid * 5 + q;
            int contrib = (i < KBOX && !selA[i]) ? 1 : 0;
            loc[q] = acc; acc += contrib;
        }
        histP[tid] = acc;
        __syncthreads();
        for (int off = 1; off < 1024; off <<= 1) {
            int v = histP[tid];
            int add = (tid >= off) ? histP[tid - off] : 0;
            __syncthreads();
            histP[tid] = v + add;
            __syncthreads();
        }
        int excl = tid ? histP[tid - 1] : 0;
        #pragma unroll
        for (int q = 0; q < 5; ++q) {
            int i = tid * 5 + q;
            if (i < KBOX && !selA[i]) {
                int p = total_sel + excl + loc[q];
                if (p < BATCH) { out_idx[b * BATCH + p] = (float)i; out_lab[b * BATCH + p] = -1.0f; }
            }
        }
    }
}

extern "C" void kernel_launch(void* const* d_in, const int* in_sizes, int n_in,
                              void* d_out, int out_size, void* d_ws, size_t ws_size,
                              hipStream_t stream) {
    const float* gt_boxes   = (const float*)d_in[0];
    const float* prop_boxes = (const float*)d_in[1];
    const int*   gt_classes = (const int*)d_in[2];
    const float* rand_pri   = (const float*)d_in[3];

    float* out = (float*)d_out;
    const size_t off_iou  = 0;
    const size_t off_midx = (size_t)Bimg * Mgt * KBOX;
    const size_t off_mlab = off_midx + (size_t)Bimg * KBOX;
    const size_t off_idx  = off_mlab + (size_t)Bimg * KBOX;
    const size_t off_lab  = off_idx  + (size_t)Bimg * BATCH;

    dim3 gridA((KBOX / 4 + 255) / 256, Bimg);   // 5 x 32
    iou_match_kernel<<<gridA, 256, 0, stream>>>(
        gt_boxes, prop_boxes,
        out + off_iou, out + off_midx, out + off_mlab);

    sample_kernel<<<Bimg, 1024, 0, stream>>>(
        gt_classes, rand_pri,
        out + off_midx, out + off_mlab,
        out + off_idx, out + off_lab);
}

// Round 4
// 65.895 us; speedup vs baseline: 2.9446x; 1.8571x over previous
//
#include <hip/hip_runtime.h>
#include <hip/hip_bf16.h>

#define Bimg 32
#define Mgt 256
#define Nprop 4000
#define KBOX (Nprop + Mgt)   // 4256
#define NCLS 80
#define BATCH 512
#define NFG_CAP 128
#define NBINS 1024
#define BINCAP 1024
#define MT 32                 // m-rows per block
#define MS (Mgt / MT)         // 8 m-slices
#define KCH ((KBOX + 1023) / 1024)  // 5 column chunks (256 thr * 4 cols)

typedef float f32x4 __attribute__((ext_vector_type(4)));

// ---------------- Kernel A: IoU tiles + per-slice partial argmax ----------------
__global__ __launch_bounds__(256) void iou_part_kernel(
    const float* __restrict__ gt_boxes,     // [B,M,4]
    const float* __restrict__ prop_boxes,   // [B,N,4]
    float* __restrict__ out_iou,            // [B,M,K]
    unsigned long long* __restrict__ part)  // [B,MS,K] packed keys
{
    const int b  = blockIdx.z;
    const int ms = blockIdx.y;
    const int m0 = ms * MT;
    const int k0 = (blockIdx.x * 256 + threadIdx.x) * 4;

    __shared__ float4 gbox[MT];
    __shared__ float  garea[MT];
    if (threadIdx.x < MT) {
        float4 g = ((const float4*)(gt_boxes + (size_t)b * Mgt * 4))[m0 + threadIdx.x];
        gbox[threadIdx.x] = g;
        garea[threadIdx.x] = (g.z - g.x) * (g.w - g.y);
    }
    __syncthreads();
    if (k0 >= KBOX) return;

    float4 bx[4]; float a2[4];
    if (k0 < Nprop) {   // Nprop % 4 == 0 -> no straddle
        const float4* pp = (const float4*)(prop_boxes + (size_t)b * Nprop * 4);
        #pragma unroll
        for (int c = 0; c < 4; ++c) bx[c] = pp[k0 + c];
    } else {
        const float4* gg = (const float4*)(gt_boxes + (size_t)b * Mgt * 4);
        #pragma unroll
        for (int c = 0; c < 4; ++c) bx[c] = gg[k0 - Nprop + c];
    }
    #pragma unroll
    for (int c = 0; c < 4; ++c) a2[c] = (bx[c].z - bx[c].x) * (bx[c].w - bx[c].y);

    unsigned long long bk[4] = {0ull, 0ull, 0ull, 0ull};
    float* orow = out_iou + (size_t)b * Mgt * KBOX + (size_t)m0 * KBOX + k0;

    for (int mm = 0; mm < MT; ++mm) {
        float4 g = gbox[mm];
        float ga = garea[mm];
        float io[4];
        #pragma unroll
        for (int c = 0; c < 4; ++c) {
            float ltx = fmaxf(g.x, bx[c].x), lty = fmaxf(g.y, bx[c].y);
            float rbx = fminf(g.z, bx[c].z), rby = fminf(g.w, bx[c].w);
            float w = fmaxf(rbx - ltx, 0.0f);
            float h = fmaxf(rby - lty, 0.0f);
            float inter = w * h;
            float uni = ga + a2[c] - inter;
            float iou = (inter > 0.0f) ? (inter / uni) : 0.0f;
            io[c] = iou;
            unsigned long long key =
                ((unsigned long long)__float_as_uint(iou) << 8) |
                (unsigned long long)(255 - (m0 + mm));
            if (key > bk[c]) bk[c] = key;   // max-key == strict-> first-argmax
        }
        f32x4 res = { io[0], io[1], io[2], io[3] };
        __builtin_nontemporal_store(res, (f32x4*)(orow + (size_t)mm * KBOX));
    }

    unsigned long long* pr = part + ((size_t)b * MS + ms) * KBOX + k0;
    *(ulonglong2*)(pr)     = make_ulonglong2(bk[0], bk[1]);
    *(ulonglong2*)(pr + 2) = make_ulonglong2(bk[2], bk[3]);
}

// ---------------- Kernel A2: reduce partials -> matched_idxs / matched_labels ----------------
__global__ __launch_bounds__(256) void match_reduce_kernel(
    const unsigned long long* __restrict__ part,  // [B,MS,K]
    float* __restrict__ out_midx,                 // [B,K]
    float* __restrict__ out_mlab)                 // [B,K]
{
    const int b = blockIdx.y;
    const int k = blockIdx.x * 256 + threadIdx.x;
    if (k >= KBOX) return;
    unsigned long long best = 0ull;
    #pragma unroll
    for (int s = 0; s < MS; ++s) {
        unsigned long long key = part[((size_t)b * MS + s) * KBOX + k];
        if (key > best) best = key;
    }
    float v = __uint_as_float((unsigned)(best >> 8));
    int   m = 255 - (int)(best & 0xFFull);
    out_midx[(size_t)b * KBOX + k] = (float)m;
    out_mlab[(size_t)b * KBOX + k] = (v >= 0.5f) ? 1.0f : 0.0f;
}

// ---------------- Kernel B: histogram-select + 512-sort ----------------
__global__ __launch_bounds__(1024) void sample_kernel(
    const int*   __restrict__ gt_classes,   // [B,M]
    const float* __restrict__ pri,          // [B,K]
    const float* __restrict__ midx,         // [B,K]
    const float* __restrict__ mlab,         // [B,K]
    float* __restrict__ out_idx,            // [B,512]
    float* __restrict__ out_lab)            // [B,512]
{
    const int b   = blockIdx.x;
    const int tid = threadIdx.x;

    __shared__ unsigned long long keys[KBOX];     // 34 KB
    __shared__ unsigned short     clsS[KBOX];     // 8.5 KB
    __shared__ unsigned char      selA[KBOX];     // 4.25 KB
    __shared__ int histP[NBINS];                  // fg low16 | bg high16
    __shared__ int sufP[NBINS];
    __shared__ unsigned long long binFG[BINCAP];  // 8 KB
    __shared__ unsigned long long binBG[BINCAP];  // 8 KB
    __shared__ unsigned long long selKeys[BATCH]; // 4 KB
    __shared__ int cntF, cntB, cntSel, sTF, sTB;

    histP[tid] = 0;
    if (tid == 0) { cntF = 0; cntB = 0; cntSel = 0; sTF = -1; sTB = -1; }
    __syncthreads();

    for (int i = tid; i < KBOX; i += 1024) {
        float p  = pri[(size_t)b * KBOX + i];
        int   mi = (int)midx[(size_t)b * KBOX + i];
        float ml = mlab[(size_t)b * KBOX + i];
        int c = (ml != 0.0f) ? gt_classes[b * Mgt + mi] : NCLS;
        clsS[i] = (unsigned short)c;
        selA[i] = 0;
        unsigned pb = __float_as_uint(p);   // pri in [0,1): monotone as uint
        keys[i] = ((unsigned long long)pb << 32) |
                  (unsigned long long)(0xFFFFFFFFu - (unsigned)i);
        int bucket = (int)(p * (float)NBINS);
        bucket = min(max(bucket, 0), NBINS - 1);
        atomicAdd(&histP[bucket], (c < NCLS) ? 1 : (1 << 16));
    }
    __syncthreads();

    sufP[tid] = histP[tid];
    __syncthreads();
    for (int off = 1; off < NBINS; off <<= 1) {
        int v = sufP[tid];
        int add = (tid + off < NBINS) ? sufP[tid + off] : 0;
        __syncthreads();
        sufP[tid] = v + add;
        __syncthreads();
    }
    const int total_fg = sufP[0] & 0xFFFF;
    const int total_bg = (sufP[0] >> 16) & 0xFFFF;
    const int num_fg = min(total_fg, NFG_CAP);
    const int num_bg = min(total_bg, BATCH - num_fg);

    {
        int sf  = sufP[tid] & 0xFFFF;
        int sfn = (tid < NBINS - 1) ? (sufP[tid + 1] & 0xFFFF) : 0;
        if (num_fg > 0 && sf >= num_fg && sfn < num_fg) sTF = tid;
        int sb  = (sufP[tid] >> 16) & 0xFFFF;
        int sbn = (tid < NBINS - 1) ? ((sufP[tid + 1] >> 16) & 0xFFFF) : 0;
        if (num_bg > 0 && sb >= num_bg && sbn < num_bg) sTB = tid;
    }
    __syncthreads();
    const int tF = sTF, tB = sTB;
    const int aboveF = (tF >= 0 && tF < NBINS - 1) ? (sufP[tF + 1] & 0xFFFF) : 0;
    const int aboveB = (tB >= 0 && tB < NBINS - 1) ? ((sufP[tB + 1] >> 16) & 0xFFFF) : 0;
    const int needF = num_fg - aboveF;
    const int needB = num_bg - aboveB;

    for (int i = tid; i < KBOX; i += 1024) {
        unsigned long long key = keys[i];
        float p = __uint_as_float((unsigned)(key >> 32));
        int bucket = (int)(p * (float)NBINS);
        bucket = min(max(bucket, 0), NBINS - 1);
        if (clsS[i] < NCLS) {
            if (tF >= 0) {
                if (bucket > tF) selA[i] = 1;
                else if (bucket == tF) { int j = atomicAdd(&cntF, 1); if (j < BINCAP) binFG[j] = key; }
            }
        } else {
            if (tB >= 0) {
                if (bucket > tB) selA[i] = 1;
                else if (bucket == tB) { int j = atomicAdd(&cntB, 1); if (j < BINCAP) binBG[j] = key; }
            }
        }
    }
    __syncthreads();

    {
        int cf = min(cntF, BINCAP);
        for (int j = tid; j < cf; j += 1024) {
            unsigned long long key = binFG[j];
            int rank = 0;
            for (int l = 0; l < cf; ++l) rank += (binFG[l] > key) ? 1 : 0;
            if (rank < needF) { unsigned kk = 0xFFFFFFFFu - (unsigned)(key & 0xFFFFFFFFull); selA[kk] = 1; }
        }
        int cb = min(cntB, BINCAP);
        for (int j = tid; j < cb; j += 1024) {
            unsigned long long key = binBG[j];
            int rank = 0;
            for (int l = 0; l < cb; ++l) rank += (binBG[l] > key) ? 1 : 0;
            if (rank < needB) { unsigned kk = 0xFFFFFFFFu - (unsigned)(key & 0xFFFFFFFFull); selA[kk] = 1; }
        }
    }
    __syncthreads();

    const int total_sel = num_fg + num_bg;
    if (tid < BATCH && tid >= total_sel) selKeys[tid] = 0ull;
    for (int i = tid; i < KBOX; i += 1024) {
        if (selA[i]) {
            int p = atomicAdd(&cntSel, 1);
            selKeys[p] = keys[i];
        }
    }
    __syncthreads();

    for (int k2 = 2; k2 <= BATCH; k2 <<= 1) {
        for (int j = k2 >> 1; j > 0; j >>= 1) {
            if (tid < BATCH) {
                int i = tid, ixj = i ^ j;
                if (ixj > i) {
                    unsigned long long a = selKeys[i], c2 = selKeys[ixj];
                    bool up = ((i & k2) == 0);
                    if (up ? (a < c2) : (a > c2)) { selKeys[i] = c2; selKeys[ixj] = a; }
                }
            }
            __syncthreads();
        }
    }

    if (tid < BATCH) {
        unsigned long long key = selKeys[tid];
        if (key != 0ull) {
            unsigned kk = 0xFFFFFFFFu - (unsigned)(key & 0xFFFFFFFFull);
            out_idx[b * BATCH + tid] = (float)kk;
            out_lab[b * BATCH + tid] = (float)clsS[kk];
        }
    }

    if (total_sel < BATCH) {
        __syncthreads();
        int loc[5]; int acc = 0;
        #pragma unroll
        for (int q = 0; q < 5; ++q) {
            int i = tid * 5 + q;
            int contrib = (i < KBOX && !selA[i]) ? 1 : 0;
            loc[q] = acc; acc += contrib;
        }
        histP[tid] = acc;
        __syncthreads();
        for (int off = 1; off < 1024; off <<= 1) {
            int v = histP[tid];
            int add = (tid >= off) ? histP[tid - off] : 0;
            __syncthreads();
            histP[tid] = v + add;
            __syncthreads();
        }
        int excl = tid ? histP[tid - 1] : 0;
        #pragma unroll
        for (int q = 0; q < 5; ++q) {
            int i = tid * 5 + q;
            if (i < KBOX && !selA[i]) {
                int p = total_sel + excl + loc[q];
                if (p < BATCH) { out_idx[b * BATCH + p] = (float)i; out_lab[b * BATCH + p] = -1.0f; }
            }
        }
    }
}

extern "C" void kernel_launch(void* const* d_in, const int* in_sizes, int n_in,
                              void* d_out, int out_size, void* d_ws, size_t ws_size,
                              hipStream_t stream) {
    const float* gt_boxes   = (const float*)d_in[0];
    const float* prop_boxes = (const float*)d_in[1];
    const int*   gt_classes = (const int*)d_in[2];
    const float* rand_pri   = (const float*)d_in[3];

    float* out = (float*)d_out;
    const size_t off_iou  = 0;
    const size_t off_midx = (size_t)Bimg * Mgt * KBOX;
    const size_t off_mlab = off_midx + (size_t)Bimg * KBOX;
    const size_t off_idx  = off_mlab + (size_t)Bimg * KBOX;
    const size_t off_lab  = off_idx  + (size_t)Bimg * BATCH;

    unsigned long long* part = (unsigned long long*)d_ws;  // [B,MS,K] = 8.7 MB

    dim3 gridA(KCH, MS, Bimg);   // 5 x 8 x 32 = 1280 blocks
    iou_part_kernel<<<gridA, 256, 0, stream>>>(
        gt_boxes, prop_boxes, out + off_iou, part);

    dim3 gridR((KBOX + 255) / 256, Bimg);  // 17 x 32
    match_reduce_kernel<<<gridR, 256, 0, stream>>>(
        part, out + off_midx, out + off_mlab);

    sample_kernel<<<Bimg, 1024, 0, stream>>>(
        gt_classes, rand_pri,
        out + off_midx, out + off_mlab,
        out + off_idx, out + off_lab);
}